// Round 16
// baseline (1605.877 us; speedup 1.0000x reference)
//
#include <hip/hip_runtime.h>
#include <hip/hip_bf16.h>
#include <math.h>

#define H    1024
#define NST  64
#define LAYN 2
#define BSZ  32
#define TLEN 512
#define NSTEPS 16
#define H2   2048
#define FLAGSTRIDE 32

typedef __attribute__((ext_vector_type(8))) short bf16x8;
typedef __attribute__((ext_vector_type(4))) short bf16x4;
typedef __attribute__((ext_vector_type(4))) float f32x4;

__device__ __forceinline__ float gelu_f(float x){
    return 0.5f*x*(1.0f+erff(x*0.7071067811865475f));
}
__device__ __forceinline__ float sigm_f(float x){
    return 1.0f/(1.0f+expf(-x));
}
__device__ __forceinline__ short bfbits(float x){
    __hip_bfloat16 h = __float2bfloat16(x);
    return *(short*)&h;
}
__device__ __forceinline__ float bf2f(short s){
    unsigned int u = ((unsigned int)(unsigned short)s) << 16;
    return __uint_as_float(u);
}
__device__ __forceinline__ void gload16(const void* g, void* l){
    __builtin_amdgcn_global_load_lds((const __attribute__((address_space(1))) void*)g,
                                     (__attribute__((address_space(3))) void*)l, 16, 0, 0);
}
// relaxed agent-scope data path (validated rounds 12-15)
__device__ __forceinline__ void ast(float* p, float v){
    __hip_atomic_store(p, v, __ATOMIC_RELAXED, __HIP_MEMORY_SCOPE_AGENT);
}
__device__ __forceinline__ float ald(const float* p){
    return __hip_atomic_load(p, __ATOMIC_RELAXED, __HIP_MEMORY_SCOPE_AGENT);
}
__device__ __forceinline__ void astu(unsigned int* p, unsigned int v){
    __hip_atomic_store(p, v, __ATOMIC_RELAXED, __HIP_MEMORY_SCOPE_AGENT);
}
__device__ __forceinline__ unsigned int aldu(const unsigned int* p){
    return __hip_atomic_load(p, __ATOMIC_RELAXED, __HIP_MEMORY_SCOPE_AGENT);
}

// ---------------- discretized SSM params ----------------
__global__ void k_precompute(const float* __restrict__ log_dt,
                             const float* __restrict__ Are, const float* __restrict__ Aim,
                             const float* __restrict__ Bre, const float* __restrict__ Bim,
                             float* __restrict__ dAr, float* __restrict__ dAi,
                             float* __restrict__ dBr, float* __restrict__ dBi){
    int i = blockIdx.x*256 + threadIdx.x;
    if (i >= LAYN*H*NST) return;
    int lh = i / NST;
    float dt = expf(log_dt[lh]);
    float ar = Are[i], ai = Aim[i];
    float e  = expf(dt*ar);
    float sa, ca; sincosf(dt*ai, &sa, &ca);
    float dar = e*ca, dai = e*sa;
    float zr = dar-1.0f, zi = dai;
    float inv = 1.0f/(ar*ar + ai*ai);
    float wr = (zr*ar + zi*ai)*inv;
    float wi = (zi*ar - zr*ai)*inv;
    float br = Bre[i], bi = Bim[i];
    dAr[i]=dar; dAi[i]=dai;
    dBr[i]=wr*br - wi*bi;
    dBi[i]=wr*bi + wi*br;
}

// ---------------- in_proj ----------------
__global__ void k_inproj_x(const float* __restrict__ in, const float* __restrict__ w,
                           const float* __restrict__ bias, float* __restrict__ x){
    int i = blockIdx.x*256+threadIdx.x;          // b*T*H + t*H + h
    int h = i & (H-1);
    int bt = i >> 10;
    x[i] = in[bt]*w[h] + bias[h];
}
__global__ void k_inproj_xT(const float* __restrict__ in, const float* __restrict__ w,
                            const float* __restrict__ bias, float* __restrict__ xT){
    int i = blockIdx.x*256+threadIdx.x;          // b*H*T + h*T + t
    int t = i & (TLEN-1);
    int bh = i >> 9;
    int h = bh & (H-1);
    int b = bh >> 10;
    xT[i] = in[b*TLEN + t]*w[h] + bias[h];
}

// ---------------- S4 conv kernel gen ----------------
__global__ __launch_bounds__(64) void k_genK(
        const float* __restrict__ dAr, const float* __restrict__ dAi,
        const float* __restrict__ dBr, const float* __restrict__ dBi,
        const float* __restrict__ Cre, const float* __restrict__ Cim,
        float* __restrict__ Kbuf){
    __shared__ float trans[16][65];
    int lh = blockIdx.x;
    int lane = threadIdx.x;
    int pi = lh*NST + lane;
    float ar=dAr[pi], ai=dAi[pi];
    float br=dBr[pi], bi=dBi[pi];
    float cr=2.f*Cre[pi], ci=2.f*Cim[pi];
    float wr = cr*br - ci*bi;
    float wi = cr*bi + ci*br;
    float* Krow = Kbuf + (size_t)lh*TLEN;
    int r = lane>>2, q = lane&3;
    for (int c=0;c<TLEN/16;c++){
        #pragma unroll
        for (int i=0;i<16;i++){
            trans[i][lane] = wr;
            float nr = fmaf(wr,ar, -wi*ai);
            float ni = fmaf(wr,ai,  wi*ar);
            wr=nr; wi=ni;
        }
        __syncthreads();
        float s = 0.f;
        #pragma unroll
        for (int m=0;m<16;m++) s += trans[r][q*16+m];
        s += __shfl_xor(s,1,64);
        s += __shfl_xor(s,2,64);
        if (q==0) Krow[c*16 + r] = s;
        __syncthreads();
    }
}

// ---------------- MFMA Toeplitz conv + D*u + gelu; bf16 (B,H,T) out ----------------
__global__ __launch_bounds__(256, 2) void k_conv_mfma(
        const float* __restrict__ u,            // (B,H,T) f32
        const float* __restrict__ Kbuf,         // (L,H,T) f32
        const float* __restrict__ Dv,
        __hip_bfloat16* __restrict__ g,         // (B,H,T) bf16
        int layer){
    __shared__ short Krp[8][1040];
    __shared__ short u_s[32][520];
    int h = blockIdx.x;
    int tid = threadIdx.x;
    const float* Krow = Kbuf + ((size_t)layer*H + h)*TLEN;
    for (int idx = tid; idx < 8*1040; idx += 256){
        int c = idx / 1040, y = idx - c*1040;
        int x = y + c;
        float v = (x <= 511) ? Krow[511 - x] : 0.f;
        Krp[c][y] = bfbits(v);
    }
    for (int idx = tid; idx < 32*512; idx += 256){
        int b = idx >> 9, t = idx & 511;
        u_s[b][t] = bfbits(u[((size_t)b*H + h)*TLEN + t]);
    }
    __syncthreads();
    int w = tid >> 6, lane = tid & 63;
    int m = lane & 15, q = lane >> 4;
    f32x4 acc[8][2] = {};
    for (int jt = 0; jt < 16; ++jt){
        int jtile = jt*32;
        bf16x8 b0 = *(const bf16x8*)&u_s[m][jtile + q*8];
        bf16x8 b1 = *(const bf16x8*)&u_s[16 + m][jtile + q*8];
        int mi_min = (2*jt - w + 3) >> 2;
        if (mi_min < 0) mi_min = 0;
        #pragma unroll
        for (int mi = 0; mi < 8; ++mi){
            if (mi < mi_min) continue;
            int tb = (mi*4 + w)*16 + m;
            int x0 = 511 - tb + jtile + q*8;
            int c = x0 & 7, base = x0 - c;
            bf16x8 a = *(const bf16x8*)&Krp[c][base];
            acc[mi][0] = __builtin_amdgcn_mfma_f32_16x16x32_bf16(a, b0, acc[mi][0], 0,0,0);
            acc[mi][1] = __builtin_amdgcn_mfma_f32_16x16x32_bf16(a, b1, acc[mi][1], 0,0,0);
        }
    }
    float dv = Dv[layer*H + h];
    #pragma unroll
    for (int mi = 0; mi < 8; ++mi){
        int tb2 = (mi*4 + w)*16 + (lane>>4)*4;
        #pragma unroll
        for (int nf = 0; nf < 2; ++nf){
            int b = nf*16 + (lane & 15);
            short4 o;
            float uu0 = bf2f(u_s[b][tb2+0]);
            float uu1 = bf2f(u_s[b][tb2+1]);
            float uu2 = bf2f(u_s[b][tb2+2]);
            float uu3 = bf2f(u_s[b][tb2+3]);
            o.x = bfbits(gelu_f(fmaf(dv, uu0, acc[mi][nf][0])));
            o.y = bfbits(gelu_f(fmaf(dv, uu1, acc[mi][nf][1])));
            o.z = bfbits(gelu_f(fmaf(dv, uu2, acc[mi][nf][2])));
            o.w = bfbits(gelu_f(fmaf(dv, uu3, acc[mi][nf][3])));
            *(short4*)((short*)g + ((size_t)b*H + h)*TLEN + tb2) = o;
        }
    }
}

// ---------------- bf16 transpose (B,H,T) -> (B,T,H) ----------------
__global__ __launch_bounds__(256) void k_trcast_bf(const __hip_bfloat16* __restrict__ x,
                                                   __hip_bfloat16* __restrict__ y){
    __shared__ __hip_bfloat16 tile[32][34];
    int t0 = blockIdx.x*32, h0 = blockIdx.y*32, b = blockIdx.z;
    int tx = threadIdx.x & 31, ty = threadIdx.x >> 5;
    #pragma unroll
    for (int i=0;i<32;i+=8)
        tile[ty+i][tx] = x[((size_t)(b*H + h0+ty+i))*TLEN + t0+tx];
    __syncthreads();
    #pragma unroll
    for (int i=0;i<32;i+=8)
        y[((size_t)(b*TLEN + t0+ty+i))*H + h0+tx] = tile[tx][ty+i];
}

// ---------------- transpose (b,t,h) -> (b,h,t) f32 ----------------
__global__ __launch_bounds__(256) void k_transpose(const float* __restrict__ x, float* __restrict__ xT){
    __shared__ float tile[32][33];
    int t0 = blockIdx.x*32, h0 = blockIdx.y*32, b = blockIdx.z;
    int tx = threadIdx.x & 31, ty = threadIdx.x >> 5;
    #pragma unroll
    for (int i=0;i<32;i+=8)
        tile[ty+i][tx] = x[((size_t)(b*TLEN + t0+ty+i))*H + h0+tx];
    __syncthreads();
    #pragma unroll
    for (int i=0;i<32;i+=8)
        xT[((size_t)(b*H + h0+ty+i))*TLEN + t0+tx] = tile[tx][ty+i];
}

// ---------------- W (L,H,2H) f32 -> Wt (L,2H,H) bf16 ----------------
__global__ __launch_bounds__(256) void k_wtr(const float* __restrict__ W,
                                             __hip_bfloat16* __restrict__ Wt){
    __shared__ float tile[32][33];
    int n0 = blockIdx.x*32, k0 = blockIdx.y*32, l = blockIdx.z;
    const float* Wl = W + (size_t)l*H*H2;
    __hip_bfloat16* Wtl = Wt + (size_t)l*H*H2;
    int tx = threadIdx.x & 31, ty = threadIdx.x >> 5;
    #pragma unroll
    for (int i=0;i<32;i+=8)
        tile[ty+i][tx] = Wl[(size_t)(k0+ty+i)*H2 + n0+tx];
    __syncthreads();
    #pragma unroll
    for (int i=0;i<32;i+=8)
        Wtl[(size_t)(n0+ty+i)*H + k0+tx] = __float2bfloat16(tile[tx][ty+i]);
}

// ---------------- bf16 MFMA GEMM + bias + GLU fused (encoder) ----------------
__global__ __launch_bounds__(256) void k_gemm_glu_mfma(
        const __hip_bfloat16* __restrict__ Abf,
        const __hip_bfloat16* __restrict__ Wt,
        const float* __restrict__ bias2,         // (2048,)
        float* __restrict__ glu){                // (M,1024)
    __shared__ alignas(16) short As[128*32];
    __shared__ alignas(16) short Bs[128*32];
    const int K = 1024;
    int tid = threadIdx.x;
    int lane = tid & 63, wid = tid >> 6;
    int m0 = blockIdx.x * 128;
    int nb = blockIdx.y * 64;
    int g0 = tid, g1 = tid + 256;
    int r0 = g0 >> 2, r1 = g1 >> 2;
    int wtr0 = nb + ((r0>>6)<<5) + (r0&31) + ((r0>>5)&1)*1024;
    int wtr1 = nb + ((r1>>6)<<5) + (r1&31) + ((r1>>5)&1)*1024;
    const short* Ap = (const short*)Abf;
    const short* Bp = (const short*)Wt;
    const short* Ag0 = Ap + (size_t)(m0 + r0)*K + (g0&3)*8;
    const short* Ag1 = Ap + (size_t)(m0 + r1)*K + (g1&3)*8;
    const short* Bg0 = Bp + (size_t)wtr0*K + (g0&3)*8;
    const short* Bg1 = Bp + (size_t)wtr1*K + (g1&3)*8;
    char* AsB = (char*)As;
    char* BsB = (char*)Bs;
    int wr = wid >> 1, wc = wid & 1;
    int mo = wr*64, no = wc*64;
    f32x4 acc[4][4] = {};
    int arow = (lane & 15)*32 + (lane>>4)*8;
    for (int k0 = 0; k0 < K; k0 += 32){
        gload16(Ag0 + k0, AsB + wid*1024);
        gload16(Ag1 + k0, AsB + 4096 + wid*1024);
        gload16(Bg0 + k0, BsB + wid*1024);
        gload16(Bg1 + k0, BsB + 4096 + wid*1024);
        asm volatile("s_waitcnt vmcnt(0)" ::: "memory");
        __syncthreads();
        bf16x8 a[4], b[4];
        #pragma unroll
        for (int mi=0;mi<4;mi++)
            a[mi] = *(const bf16x8*)(As + (mo + mi*16)*32 + arow);
        #pragma unroll
        for (int ni=0;ni<4;ni++)
            b[ni] = *(const bf16x8*)(Bs + (no + ni*16)*32 + arow);
        #pragma unroll
        for (int mi=0;mi<4;mi++){
            #pragma unroll
            for (int ni=0;ni<4;ni++){
                acc[mi][ni] = __builtin_amdgcn_mfma_f32_16x16x32_bf16(a[mi], b[ni], acc[mi][ni], 0, 0, 0);
            }
        }
        __syncthreads();
    }
    int cbase = nb + wc*32 + (lane&15);
    #pragma unroll
    for (int ni=0;ni<2;ni++){
        int c = cbase + ni*16;
        float ba = bias2[c], bb = bias2[c+1024];
        #pragma unroll
        for (int mi=0;mi<4;mi++){
            #pragma unroll
            for (int r=0;r<4;r++){
                size_t m = m0 + mo + mi*16 + (lane>>4)*4 + r;
                float za = acc[mi][ni][r] + ba;
                float zb = acc[mi][ni+2][r] + bb;
                glu[m*H + c] = za * sigm_f(zb);
            }
        }
    }
}

// ---------------- LayerNorm over H per (b,t) row (encoder) ----------------
__global__ __launch_bounds__(256) void k_ln(const float* __restrict__ glu, const float* __restrict__ res,
        const float* __restrict__ gamma, const float* __restrict__ beta, float* __restrict__ outx){
    __shared__ float red[8];
    int row = blockIdx.x;
    int tid = threadIdx.x;
    float4 gv = *(const float4*)(glu + (size_t)row*H + tid*4);
    float4 rv = *(const float4*)(res + (size_t)row*H + tid*4);
    float x0=gv.x+rv.x, x1=gv.y+rv.y, x2=gv.z+rv.z, x3=gv.w+rv.w;
    float s = x0+x1+x2+x3;
    float q = x0*x0+x1*x1+x2*x2+x3*x3;
    #pragma unroll
    for (int m=32;m>=1;m>>=1){ s += __shfl_xor(s,m,64); q += __shfl_xor(q,m,64); }
    int wv = tid>>6;
    if ((tid&63)==0){ red[wv]=s; red[4+wv]=q; }
    __syncthreads();
    s = red[0]+red[1]+red[2]+red[3];
    q = red[4]+red[5]+red[6]+red[7];
    float m = s*(1.0f/H);
    float v = q*(1.0f/H) - m*m;
    float rstd = rsqrtf(v + 1e-5f);
    float4 gm = *(const float4*)(gamma + tid*4);
    float4 bt = *(const float4*)(beta + tid*4);
    float4 o;
    o.x = (x0-m)*rstd*gm.x + bt.x;
    o.y = (x1-m)*rstd*gm.y + bt.y;
    o.z = (x2-m)*rstd*gm.z + bt.z;
    o.w = (x3-m)*rstd*gm.w + bt.w;
    *(float4*)(outx + (size_t)row*H + tid*4) = o;
}

__global__ void k_ctx(const float* __restrict__ x, float* __restrict__ ctx){
    int i = blockIdx.x*256+threadIdx.x;
    int b = i>>10, h = i&(H-1);
    ctx[i] = x[((size_t)(b*TLEN + TLEN-1))*H + h];
}

// ======================= COLUMN-SLICED DECODE =======================
// 256 blocks: xcd = bid&7 owns col-pairs [128*xcd, 128*xcd+128) -> per-XCD W
// working set = 1 MB (L2-resident); every W byte amortized over all 32 batches.
// Leaders = blocks (xcd, j<4), batch b = j*8+xcd, do LN/Toeplitz-conv phases.
// Hierarchical global barrier: 32 same-XCD arrivals -> 8 cross-XCD flags -> release.
__device__ __forceinline__ void hbar(int* bar, int xcd, int j, int g, int tid){
    __syncthreads();   // drains vmcnt per wave -> block's global stores done
    if (tid == 0)
        __hip_atomic_store(&bar[(xcd*32 + j)*FLAGSTRIDE], g, __ATOMIC_RELAXED,
                           __HIP_MEMORY_SCOPE_AGENT);
    if (j == 0){
        if (tid < 32){
            int it = 0;
            while (__hip_atomic_load(&bar[(xcd*32 + tid)*FLAGSTRIDE], __ATOMIC_RELAXED,
                                     __HIP_MEMORY_SCOPE_AGENT) < g){
                __builtin_amdgcn_s_sleep(1);
                if (++it > 1000000) break;
            }
        }
        __syncthreads();
        if (tid == 0)
            __hip_atomic_store(&bar[(256 + xcd)*FLAGSTRIDE], g, __ATOMIC_RELAXED,
                               __HIP_MEMORY_SCOPE_AGENT);
        if (tid < 8){
            int it = 0;
            while (__hip_atomic_load(&bar[(256 + tid)*FLAGSTRIDE], __ATOMIC_RELAXED,
                                     __HIP_MEMORY_SCOPE_AGENT) < g){
                __builtin_amdgcn_s_sleep(1);
                if (++it > 1000000) break;
            }
        }
        __syncthreads();
        if (tid == 0)
            __hip_atomic_store(&bar[(264 + xcd)*FLAGSTRIDE], g, __ATOMIC_RELAXED,
                               __HIP_MEMORY_SCOPE_AGENT);
    }
    if (tid == 0){
        int it = 0;
        while (__hip_atomic_load(&bar[(264 + xcd)*FLAGSTRIDE], __ATOMIC_RELAXED,
                                 __HIP_MEMORY_SCOPE_AGENT) < g){
            __builtin_amdgcn_s_sleep(1);
            if (++it > 1000000) break;
        }
    }
    __syncthreads();
}

// GEMM phase: block computes its 4 col-pairs for ALL 32 batches.
// thread = (b = tid&31, ks = tid>>5 of 8 k-octants); W loads half-wave-uniform.
__device__ __forceinline__ void gemm_slice(int cp0, int tid,
        unsigned short (*u_s)[1028], float (*part)[4][2][32],
        const short* __restrict__ Wl, const float* __restrict__ b2,
        const unsigned int* __restrict__ ygel, float* __restrict__ glud){
    // stage u: 32 batches x 512 packed uints -> LDS bf16 rows (pitch 1028)
    #pragma unroll 4
    for (int i = 0; i < 64; ++i){
        int idx = i*256 + tid;
        int bb = idx >> 9, k2 = idx & 511;
        unsigned int v = aldu(&ygel[bb*512 + k2]);
        *(unsigned int*)&u_s[bb][k2*2] = v;
    }
    __syncthreads();
    int b = tid & 31, ks = tid >> 5;
    const unsigned short* ub = &u_s[b][ks*128];
    float accA[4], accB[4];
    #pragma unroll
    for (int c = 0; c < 4; ++c){
        const short* wa = Wl + (size_t)(cp0 + c)*H + ks*128;
        const short* wb = Wl + (size_t)(cp0 + c + 1024)*H + ks*128;
        float aa = 0.f, ab = 0.f;
        #pragma unroll 4
        for (int kk = 0; kk < 128; kk += 8){
            bf16x8 wva = *(const bf16x8*)(wa + kk);
            bf16x8 wvb = *(const bf16x8*)(wb + kk);
            bf16x4 u0 = *(const bf16x4*)(ub + kk);
            bf16x4 u1 = *(const bf16x4*)(ub + kk + 4);
            #pragma unroll
            for (int q = 0; q < 4; ++q){
                float uv = bf2f(u0[q]);
                aa = fmaf(uv, bf2f(wva[q]), aa);
                ab = fmaf(uv, bf2f(wvb[q]), ab);
            }
            #pragma unroll
            for (int q = 0; q < 4; ++q){
                float uv = bf2f(u1[q]);
                aa = fmaf(uv, bf2f(wva[4+q]), aa);
                ab = fmaf(uv, bf2f(wvb[4+q]), ab);
            }
        }
        accA[c] = aa; accB[c] = ab;
    }
    __syncthreads();
    #pragma unroll
    for (int c = 0; c < 4; ++c){
        part[ks][c][0][b] = accA[c];
        part[ks][c][1][b] = accB[c];
    }
    __syncthreads();
    if (tid < 128){
        int bb = tid & 31, c = tid >> 5;
        float sa = 0.f, sb = 0.f;
        #pragma unroll
        for (int q = 0; q < 8; ++q){ sa += part[q][c][0][bb]; sb += part[q][c][1][bb]; }
        int col = cp0 + c;
        ast(&glud[(size_t)bb*H + col], (sa + b2[col]) * sigm_f(sb + b2[1024 + col]));
    }
}

__global__ __launch_bounds__(256, 1) void k_decode(
        const float* __restrict__ Kbuf, const float* __restrict__ Dv,
        const __hip_bfloat16* __restrict__ Wt, const float* __restrict__ bias2,
        const float* __restrict__ lng, const float* __restrict__ lnb,
        const float* __restrict__ ctx, const float* __restrict__ headw,
        const float* __restrict__ headb,
        unsigned int* __restrict__ ygel0, unsigned int* __restrict__ ygel1,
        float* __restrict__ glud0, float* __restrict__ glud1,
        float* __restrict__ out, int* __restrict__ bar){
    __shared__ unsigned short u_s[32][1028];   // 65.8 KB
    __shared__ unsigned short hist[16][1024];  // 32.8 KB (bf16 dec history)
    __shared__ float part[8][4][2][32];        // 8 KB
    __shared__ float red[8];
    __shared__ float bitsh[16];
    int bid = blockIdx.x;
    int xcd = bid & 7, j = bid >> 3;
    int tid = threadIdx.x;
    int lane = tid & 63, wv = tid >> 6;
    bool leader = (j < 4);
    int b = j*8 + xcd;                    // leader's batch (valid when j<4)
    int cp0 = xcd*128 + j*4;              // block's col-pair base
    float4 dv0v, dv1v, lg0v, be0v, lg1v, be1v, cvxv, hwv;
    float hb = headb[0];
    if (leader){
        dv0v = *(const float4*)(Dv + tid*4);
        dv1v = *(const float4*)(Dv + H + tid*4);
        lg0v = *(const float4*)(lng + tid*4);
        be0v = *(const float4*)(lnb + tid*4);
        lg1v = *(const float4*)(lng + H + tid*4);
        be1v = *(const float4*)(lnb + H + tid*4);
        cvxv = *(const float4*)(ctx + (size_t)b*H + tid*4);
        hwv  = *(const float4*)(headw + tid*4);
    }
    if (tid < 16) bitsh[tid] = 0.f;
    __syncthreads();
    const short* Wt0 = (const short*)Wt;
    const short* Wt1 = (const short*)Wt + (size_t)H*H2;
    int g = 1;
    for (int s = 0; s < NSTEPS; ++s){
        // ===== A: leaders: LN1+head(prev)->bit,out; conv0 -> ygel0 (packed bf16) =====
        if (leader){
            if (s > 0){
                int sp = s-1;
                float x0 = ald(&glud1[(size_t)b*H + tid*4+0]);
                float x1 = ald(&glud1[(size_t)b*H + tid*4+1]);
                float x2 = ald(&glud1[(size_t)b*H + tid*4+2]);
                float x3 = ald(&glud1[(size_t)b*H + tid*4+3]);
                if (sp != 0){ x0*=2.f; x1*=2.f; x2*=2.f; x3*=2.f; }
                float su = x0+x1+x2+x3, qu = x0*x0+x1*x1+x2*x2+x3*x3;
                #pragma unroll
                for (int m=32;m>=1;m>>=1){ su += __shfl_xor(su,m,64); qu += __shfl_xor(qu,m,64); }
                if (lane==0){ red[wv]=su; red[4+wv]=qu; }
                __syncthreads();
                float S = red[0]+red[1]+red[2]+red[3];
                float Q = red[4]+red[5]+red[6]+red[7];
                float mean = S*(1.f/H), var = Q*(1.f/H)-mean*mean;
                float rstd = rsqrtf(var + 1e-5f);
                float d0 = (x0-mean)*rstd*lg1v.x + be1v.x + cvxv.x;
                float d1 = (x1-mean)*rstd*lg1v.y + be1v.y + cvxv.y;
                float d2 = (x2-mean)*rstd*lg1v.z + be1v.z + cvxv.z;
                float d3 = (x3-mean)*rstd*lg1v.w + be1v.w + cvxv.w;
                float hp = d0*hwv.x + d1*hwv.y + d2*hwv.z + d3*hwv.w;
                #pragma unroll
                for (int m=32;m>=1;m>>=1) hp += __shfl_xor(hp,m,64);
                __syncthreads();
                if (lane==0) red[wv] = hp;
                __syncthreads();
                float hs = red[0]+red[1]+red[2]+red[3] + hb;
                float bit = sigm_f(hs);
                if (tid==0){ out[b*NSTEPS + sp] = bit; bitsh[sp] = bit; }
                __syncthreads();
            }
            float bu = (s==0) ? 0.f : bitsh[s-1];
            float dvs[4] = {dv0v.x, dv0v.y, dv0v.z, dv0v.w};
            float yv[4];
            #pragma unroll
            for (int i=0;i<4;i++){
                int h = tid*4+i;
                const float* Kr = Kbuf + (size_t)h*TLEN;
                float y0 = dvs[i]*bu;
                #pragma unroll
                for (int d=0; d<16; d++){
                    int idx = s-1-d;
                    float uv = (idx >= 0) ? bitsh[idx] : 0.f;
                    y0 = fmaf(Kr[d], uv, y0);
                }
                yv[i] = gelu_f(y0);
            }
            unsigned int p0 = (unsigned int)(unsigned short)bfbits(yv[0]) |
                              ((unsigned int)(unsigned short)bfbits(yv[1]) << 16);
            unsigned int p1 = (unsigned int)(unsigned short)bfbits(yv[2]) |
                              ((unsigned int)(unsigned short)bfbits(yv[3]) << 16);
            astu(&ygel0[b*512 + tid*2],     p0);
            astu(&ygel0[b*512 + tid*2 + 1], p1);
        }
        hbar(bar, xcd, j, g++, tid);
        // ===== B: GEMM0 (all blocks, own cp slice, all 32 batches) =====
        gemm_slice(cp0, tid, u_s, part, Wt0, bias2, ygel0, glud0);
        hbar(bar, xcd, j, g++, tid);
        // ===== C: leaders: LN0 -> dec; hist push; conv1 -> ygel1 =====
        if (leader){
            float x0 = ald(&glud0[(size_t)b*H + tid*4+0]);
            float x1 = ald(&glud0[(size_t)b*H + tid*4+1]);
            float x2 = ald(&glud0[(size_t)b*H + tid*4+2]);
            float x3 = ald(&glud0[(size_t)b*H + tid*4+3]);
            if (s != 0){ x0*=2.f; x1*=2.f; x2*=2.f; x3*=2.f; }
            float su = x0+x1+x2+x3, qu = x0*x0+x1*x1+x2*x2+x3*x3;
            #pragma unroll
            for (int m=32;m>=1;m>>=1){ su += __shfl_xor(su,m,64); qu += __shfl_xor(qu,m,64); }
            if (lane==0){ red[wv]=su; red[4+wv]=qu; }
            __syncthreads();
            float S = red[0]+red[1]+red[2]+red[3];
            float Q = red[4]+red[5]+red[6]+red[7];
            float mean = S*(1.f/H), var = Q*(1.f/H)-mean*mean;
            float rstd = rsqrtf(var + 1e-5f);
            float dd[4];
            dd[0] = (x0-mean)*rstd*lg0v.x + be0v.x;
            dd[1] = (x1-mean)*rstd*lg0v.y + be0v.y;
            dd[2] = (x2-mean)*rstd*lg0v.z + be0v.z;
            dd[3] = (x3-mean)*rstd*lg0v.w + be0v.w;
            float dvs[4] = {dv1v.x, dv1v.y, dv1v.z, dv1v.w};
            float yv[4];
            #pragma unroll
            for (int i=0;i<4;i++){
                int h = tid*4+i;
                hist[s & 15][h] = (unsigned short)bfbits(dd[i]);
                const float* Kr = Kbuf + (size_t)(H+h)*TLEN;
                float y1 = dvs[i]*dd[i];
                #pragma unroll
                for (int d=0; d<16; d++){
                    int sd = s-d;
                    float uv = (sd >= 0) ? bf2f((short)hist[sd & 15][h]) : 0.f;
                    y1 = fmaf(Kr[d], uv, y1);
                }
                yv[i] = gelu_f(y1);
            }
            unsigned int p0 = (unsigned int)(unsigned short)bfbits(yv[0]) |
                              ((unsigned int)(unsigned short)bfbits(yv[1]) << 16);
            unsigned int p1 = (unsigned int)(unsigned short)bfbits(yv[2]) |
                              ((unsigned int)(unsigned short)bfbits(yv[3]) << 16);
            astu(&ygel1[b*512 + tid*2],     p0);
            astu(&ygel1[b*512 + tid*2 + 1], p1);
        }
        hbar(bar, xcd, j, g++, tid);
        // ===== D: GEMM1 =====
        gemm_slice(cp0, tid, u_s, part, Wt1, bias2 + H2, ygel1, glud1);
        hbar(bar, xcd, j, g++, tid);
    }
    // ===== tail: leaders: LN1+head of step 15 =====
    if (leader){
        float x0 = 2.f*ald(&glud1[(size_t)b*H + tid*4+0]);
        float x1 = 2.f*ald(&glud1[(size_t)b*H + tid*4+1]);
        float x2 = 2.f*ald(&glud1[(size_t)b*H + tid*4+2]);
        float x3 = 2.f*ald(&glud1[(size_t)b*H + tid*4+3]);
        float su = x0+x1+x2+x3, qu = x0*x0+x1*x1+x2*x2+x3*x3;
        #pragma unroll
        for (int m=32;m>=1;m>>=1){ su += __shfl_xor(su,m,64); qu += __shfl_xor(qu,m,64); }
        if (lane==0){ red[wv]=su; red[4+wv]=qu; }
        __syncthreads();
        float S = red[0]+red[1]+red[2]+red[3];
        float Q = red[4]+red[5]+red[6]+red[7];
        float mean = S*(1.f/H), var = Q*(1.f/H)-mean*mean;
        float rstd = rsqrtf(var + 1e-5f);
        float d0 = (x0-mean)*rstd*lg1v.x + be1v.x + cvxv.x;
        float d1 = (x1-mean)*rstd*lg1v.y + be1v.y + cvxv.y;
        float d2 = (x2-mean)*rstd*lg1v.z + be1v.z + cvxv.z;
        float d3 = (x3-mean)*rstd*lg1v.w + be1v.w + cvxv.w;
        float hp = d0*hwv.x + d1*hwv.y + d2*hwv.z + d3*hwv.w;
        #pragma unroll
        for (int m=32;m>=1;m>>=1) hp += __shfl_xor(hp,m,64);
        __syncthreads();
        if (lane==0) red[wv] = hp;
        __syncthreads();
        float hs = red[0]+red[1]+red[2]+red[3] + hb;
        if (tid==0) out[b*NSTEPS + 15] = sigm_f(hs);
    }
}

extern "C" void kernel_launch(void* const* d_in, const int* in_sizes, int n_in,
                              void* d_out, int out_size, void* d_ws, size_t ws_size,
                              hipStream_t stream) {
    const float* in_seq = (const float*)d_in[0];
    const float* inw  = (const float*)d_in[2];
    const float* inb  = (const float*)d_in[3];
    const float* log_dt = (const float*)d_in[4];
    const float* Are = (const float*)d_in[5];
    const float* Aim = (const float*)d_in[6];
    const float* Bre = (const float*)d_in[7];
    const float* Bim = (const float*)d_in[8];
    const float* Cre = (const float*)d_in[9];
    const float* Cim = (const float*)d_in[10];
    const float* Dv  = (const float*)d_in[11];
    const float* outw = (const float*)d_in[12];
    const float* outb = (const float*)d_in[13];
    const float* lng = (const float*)d_in[14];
    const float* lnb = (const float*)d_in[15];
    const float* headw = (const float*)d_in[16];
    const float* headb = (const float*)d_in[17];
    float* out = (float*)d_out;

    float* ws = (float*)d_ws;
    size_t off = 0;
    auto alloc = [&](size_t n){ float* p = ws + off; off += n; return p; };
    float* dAr = alloc((size_t)LAYN*H*NST);
    float* dAi = alloc((size_t)LAYN*H*NST);
    float* dBr = alloc((size_t)LAYN*H*NST);
    float* dBi = alloc((size_t)LAYN*H*NST);
    float* Kbuf = alloc((size_t)LAYN*H*TLEN);
    float* bufA = alloc((size_t)BSZ*TLEN*H);                              // 67MB
    float* bufB = alloc((size_t)BSZ*TLEN*H);                              // 67MB
    __hip_bfloat16* gbf = (__hip_bfloat16*)alloc((size_t)BSZ*TLEN*H/2);   // 33.5MB
    __hip_bfloat16* Abf = (__hip_bfloat16*)alloc((size_t)BSZ*TLEN*H/2);   // 33.5MB
    __hip_bfloat16* Wt  = (__hip_bfloat16*)alloc((size_t)LAYN*H*H2/2);    // 8.4MB
    float* ctx = alloc((size_t)BSZ*H);
    unsigned int* ygel0 = (unsigned int*)alloc((size_t)BSZ*512);
    unsigned int* ygel1 = (unsigned int*)alloc((size_t)BSZ*512);
    float* glud0 = alloc((size_t)BSZ*H);
    float* glud1 = alloc((size_t)BSZ*H);
    int*   bar  = (int*)alloc((size_t)272*FLAGSTRIDE);
    // total ~217 MB (round-3's proven 241.7 MB OK; round-4's 283.6 MB crashed)

    k_precompute<<<(LAYN*H*NST+255)/256, 256, 0, stream>>>(log_dt,Are,Aim,Bre,Bim,dAr,dAi,dBr,dBi);
    k_genK<<<LAYN*H, 64, 0, stream>>>(dAr,dAi,dBr,dBi,Cre,Cim,Kbuf);
    k_wtr<<<dim3(H2/32, H/32, LAYN), 256, 0, stream>>>(outw, Wt);
    k_inproj_x <<<(BSZ*TLEN*H)/256, 256, 0, stream>>>(in_seq, inw, inb, bufA);
    k_inproj_xT<<<(BSZ*TLEN*H)/256, 256, 0, stream>>>(in_seq, inw, inb, bufB);

    // ---- layer 0: res = bufA (b,t,h); xT = bufB (b,h,t)
    k_conv_mfma<<<dim3(H), 256, 0, stream>>>(bufB, Kbuf, Dv, gbf, 0);
    k_trcast_bf<<<dim3(TLEN/32, H/32, BSZ), 256, 0, stream>>>(gbf, Abf);
    k_gemm_glu_mfma<<<dim3(BSZ*TLEN/128, H/64), 256, 0, stream>>>(Abf, Wt, outb, bufB);
    k_ln<<<BSZ*TLEN, 256, 0, stream>>>(bufB, bufA, lng, lnb, bufA);
    k_transpose<<<dim3(16,32,32), 256, 0, stream>>>(bufA, bufB);

    // ---- layer 1
    k_conv_mfma<<<dim3(H), 256, 0, stream>>>(bufB, Kbuf, Dv, gbf, 1);
    k_trcast_bf<<<dim3(TLEN/32, H/32, BSZ), 256, 0, stream>>>(gbf, Abf);
    k_gemm_glu_mfma<<<dim3(BSZ*TLEN/128, H/64), 256, 0, stream>>>(Abf, Wt + (size_t)H*H2, outb + H2, bufB);
    k_ln<<<BSZ*TLEN, 256, 0, stream>>>(bufB, bufA, lng+H, lnb+H, bufA);

    k_ctx<<<(BSZ*H)/256, 256, 0, stream>>>(bufA, ctx);

    // ---- decode: column-sliced (W L2-resident per XCD), hierarchical barriers
    hipMemsetAsync(bar, 0, sizeof(int)*(size_t)272*FLAGSTRIDE, stream);
    k_decode<<<256, 256, 0, stream>>>(Kbuf, Dv, Wt, outb, lng, lnb,
                                      ctx, headw, headb,
                                      ygel0, ygel1, glud0, glud1, out, bar);
}

// Round 17
// 1211.416 us; speedup vs baseline: 1.3256x; 1.3256x over previous
//
#include <hip/hip_runtime.h>
#include <hip/hip_bf16.h>
#include <math.h>

#define H    1024
#define NST  64
#define LAYN 2
#define BSZ  32
#define TLEN 512
#define NSTEPS 16
#define H2   2048
#define FLAGSTRIDE 32
#define NGRP 8

typedef __attribute__((ext_vector_type(8))) short bf16x8;
typedef __attribute__((ext_vector_type(4))) float f32x4;

__device__ __forceinline__ float gelu_f(float x){
    return 0.5f*x*(1.0f+erff(x*0.7071067811865475f));
}
__device__ __forceinline__ float sigm_f(float x){
    return 1.0f/(1.0f+expf(-x));
}
__device__ __forceinline__ short bfbits(float x){
    __hip_bfloat16 h = __float2bfloat16(x);
    return *(short*)&h;
}
__device__ __forceinline__ float bf2f(short s){
    unsigned int u = ((unsigned int)(unsigned short)s) << 16;
    return __uint_as_float(u);
}
__device__ __forceinline__ void gload16(const void* g, void* l){
    __builtin_amdgcn_global_load_lds((const __attribute__((address_space(1))) void*)g,
                                     (__attribute__((address_space(3))) void*)l, 16, 0, 0);
}
// relaxed agent-scope data path (validated rounds 12-16)
__device__ __forceinline__ void ast(float* p, float v){
    __hip_atomic_store(p, v, __ATOMIC_RELAXED, __HIP_MEMORY_SCOPE_AGENT);
}
__device__ __forceinline__ float ald(const float* p){
    return __hip_atomic_load(p, __ATOMIC_RELAXED, __HIP_MEMORY_SCOPE_AGENT);
}

// ---------------- discretized SSM params ----------------
__global__ void k_precompute(const float* __restrict__ log_dt,
                             const float* __restrict__ Are, const float* __restrict__ Aim,
                             const float* __restrict__ Bre, const float* __restrict__ Bim,
                             float* __restrict__ dAr, float* __restrict__ dAi,
                             float* __restrict__ dBr, float* __restrict__ dBi){
    int i = blockIdx.x*256 + threadIdx.x;
    if (i >= LAYN*H*NST) return;
    int lh = i / NST;
    float dt = expf(log_dt[lh]);
    float ar = Are[i], ai = Aim[i];
    float e  = expf(dt*ar);
    float sa, ca; sincosf(dt*ai, &sa, &ca);
    float dar = e*ca, dai = e*sa;
    float zr = dar-1.0f, zi = dai;
    float inv = 1.0f/(ar*ar + ai*ai);
    float wr = (zr*ar + zi*ai)*inv;
    float wi = (zi*ar - zr*ai)*inv;
    float br = Bre[i], bi = Bim[i];
    dAr[i]=dar; dAi[i]=dai;
    dBr[i]=wr*br - wi*bi;
    dBi[i]=wr*bi + wi*br;
}

// ---------------- in_proj ----------------
__global__ void k_inproj_x(const float* __restrict__ in, const float* __restrict__ w,
                           const float* __restrict__ bias, float* __restrict__ x){
    int i = blockIdx.x*256+threadIdx.x;          // b*T*H + t*H + h
    int h = i & (H-1);
    int bt = i >> 10;
    x[i] = in[bt]*w[h] + bias[h];
}
__global__ void k_inproj_xT(const float* __restrict__ in, const float* __restrict__ w,
                            const float* __restrict__ bias, float* __restrict__ xT){
    int i = blockIdx.x*256+threadIdx.x;          // b*H*T + h*T + t
    int t = i & (TLEN-1);
    int bh = i >> 9;
    int h = bh & (H-1);
    int b = bh >> 10;
    xT[i] = in[b*TLEN + t]*w[h] + bias[h];
}

// ---------------- S4 conv kernel gen ----------------
__global__ __launch_bounds__(64) void k_genK(
        const float* __restrict__ dAr, const float* __restrict__ dAi,
        const float* __restrict__ dBr, const float* __restrict__ dBi,
        const float* __restrict__ Cre, const float* __restrict__ Cim,
        float* __restrict__ Kbuf){
    __shared__ float trans[16][65];
    int lh = blockIdx.x;
    int lane = threadIdx.x;
    int pi = lh*NST + lane;
    float ar=dAr[pi], ai=dAi[pi];
    float br=dBr[pi], bi=dBi[pi];
    float cr=2.f*Cre[pi], ci=2.f*Cim[pi];
    float wr = cr*br - ci*bi;
    float wi = cr*bi + ci*br;
    float* Krow = Kbuf + (size_t)lh*TLEN;
    int r = lane>>2, q = lane&3;
    for (int c=0;c<TLEN/16;c++){
        #pragma unroll
        for (int i=0;i<16;i++){
            trans[i][lane] = wr;
            float nr = fmaf(wr,ar, -wi*ai);
            float ni = fmaf(wr,ai,  wi*ar);
            wr=nr; wi=ni;
        }
        __syncthreads();
        float s = 0.f;
        #pragma unroll
        for (int m=0;m<16;m++) s += trans[r][q*16+m];
        s += __shfl_xor(s,1,64);
        s += __shfl_xor(s,2,64);
        if (q==0) Krow[c*16 + r] = s;
        __syncthreads();
    }
}

// ---------------- MFMA Toeplitz conv + D*u + gelu; bf16 (B,H,T) out ----------------
__global__ __launch_bounds__(256, 2) void k_conv_mfma(
        const float* __restrict__ u,            // (B,H,T) f32
        const float* __restrict__ Kbuf,         // (L,H,T) f32
        const float* __restrict__ Dv,
        __hip_bfloat16* __restrict__ g,         // (B,H,T) bf16
        int layer){
    __shared__ short Krp[8][1040];
    __shared__ short u_s[32][520];
    int h = blockIdx.x;
    int tid = threadIdx.x;
    const float* Krow = Kbuf + ((size_t)layer*H + h)*TLEN;
    for (int idx = tid; idx < 8*1040; idx += 256){
        int c = idx / 1040, y = idx - c*1040;
        int x = y + c;
        float v = (x <= 511) ? Krow[511 - x] : 0.f;
        Krp[c][y] = bfbits(v);
    }
    for (int idx = tid; idx < 32*512; idx += 256){
        int b = idx >> 9, t = idx & 511;
        u_s[b][t] = bfbits(u[((size_t)b*H + h)*TLEN + t]);
    }
    __syncthreads();
    int w = tid >> 6, lane = tid & 63;
    int m = lane & 15, q = lane >> 4;
    f32x4 acc[8][2] = {};
    for (int jt = 0; jt < 16; ++jt){
        int jtile = jt*32;
        bf16x8 b0 = *(const bf16x8*)&u_s[m][jtile + q*8];
        bf16x8 b1 = *(const bf16x8*)&u_s[16 + m][jtile + q*8];
        int mi_min = (2*jt - w + 3) >> 2;
        if (mi_min < 0) mi_min = 0;
        #pragma unroll
        for (int mi = 0; mi < 8; ++mi){
            if (mi < mi_min) continue;
            int tb = (mi*4 + w)*16 + m;
            int x0 = 511 - tb + jtile + q*8;
            int c = x0 & 7, base = x0 - c;
            bf16x8 a = *(const bf16x8*)&Krp[c][base];
            acc[mi][0] = __builtin_amdgcn_mfma_f32_16x16x32_bf16(a, b0, acc[mi][0], 0,0,0);
            acc[mi][1] = __builtin_amdgcn_mfma_f32_16x16x32_bf16(a, b1, acc[mi][1], 0,0,0);
        }
    }
    float dv = Dv[layer*H + h];
    #pragma unroll
    for (int mi = 0; mi < 8; ++mi){
        int tb2 = (mi*4 + w)*16 + (lane>>4)*4;
        #pragma unroll
        for (int nf = 0; nf < 2; ++nf){
            int b = nf*16 + (lane & 15);
            short4 o;
            float uu0 = bf2f(u_s[b][tb2+0]);
            float uu1 = bf2f(u_s[b][tb2+1]);
            float uu2 = bf2f(u_s[b][tb2+2]);
            float uu3 = bf2f(u_s[b][tb2+3]);
            o.x = bfbits(gelu_f(fmaf(dv, uu0, acc[mi][nf][0])));
            o.y = bfbits(gelu_f(fmaf(dv, uu1, acc[mi][nf][1])));
            o.z = bfbits(gelu_f(fmaf(dv, uu2, acc[mi][nf][2])));
            o.w = bfbits(gelu_f(fmaf(dv, uu3, acc[mi][nf][3])));
            *(short4*)((short*)g + ((size_t)b*H + h)*TLEN + tb2) = o;
        }
    }
}

// ---------------- bf16 transpose (B,H,T) -> (B,T,H) ----------------
__global__ __launch_bounds__(256) void k_trcast_bf(const __hip_bfloat16* __restrict__ x,
                                                   __hip_bfloat16* __restrict__ y){
    __shared__ __hip_bfloat16 tile[32][34];
    int t0 = blockIdx.x*32, h0 = blockIdx.y*32, b = blockIdx.z;
    int tx = threadIdx.x & 31, ty = threadIdx.x >> 5;
    #pragma unroll
    for (int i=0;i<32;i+=8)
        tile[ty+i][tx] = x[((size_t)(b*H + h0+ty+i))*TLEN + t0+tx];
    __syncthreads();
    #pragma unroll
    for (int i=0;i<32;i+=8)
        y[((size_t)(b*TLEN + t0+ty+i))*H + h0+tx] = tile[tx][ty+i];
}

// ---------------- transpose (b,t,h) -> (b,h,t) f32 ----------------
__global__ __launch_bounds__(256) void k_transpose(const float* __restrict__ x, float* __restrict__ xT){
    __shared__ float tile[32][33];
    int t0 = blockIdx.x*32, h0 = blockIdx.y*32, b = blockIdx.z;
    int tx = threadIdx.x & 31, ty = threadIdx.x >> 5;
    #pragma unroll
    for (int i=0;i<32;i+=8)
        tile[ty+i][tx] = x[((size_t)(b*TLEN + t0+ty+i))*H + h0+tx];
    __syncthreads();
    #pragma unroll
    for (int i=0;i<32;i+=8)
        xT[((size_t)(b*H + h0+ty+i))*TLEN + t0+tx] = tile[tx][ty+i];
}

// ---------------- W (L,H,2H) f32 -> Wt (L,2H,H) bf16 ----------------
__global__ __launch_bounds__(256) void k_wtr(const float* __restrict__ W,
                                             __hip_bfloat16* __restrict__ Wt){
    __shared__ float tile[32][33];
    int n0 = blockIdx.x*32, k0 = blockIdx.y*32, l = blockIdx.z;
    const float* Wl = W + (size_t)l*H*H2;
    __hip_bfloat16* Wtl = Wt + (size_t)l*H*H2;
    int tx = threadIdx.x & 31, ty = threadIdx.x >> 5;
    #pragma unroll
    for (int i=0;i<32;i+=8)
        tile[ty+i][tx] = Wl[(size_t)(k0+ty+i)*H2 + n0+tx];
    __syncthreads();
    #pragma unroll
    for (int i=0;i<32;i+=8)
        Wtl[(size_t)(n0+ty+i)*H + k0+tx] = __float2bfloat16(tile[tx][ty+i]);
}

// ---------------- bf16 MFMA GEMM + bias + GLU fused (encoder) ----------------
__global__ __launch_bounds__(256) void k_gemm_glu_mfma(
        const __hip_bfloat16* __restrict__ Abf,
        const __hip_bfloat16* __restrict__ Wt,
        const float* __restrict__ bias2,         // (2048,)
        float* __restrict__ glu){                // (M,1024)
    __shared__ alignas(16) short As[128*32];
    __shared__ alignas(16) short Bs[128*32];
    const int K = 1024;
    int tid = threadIdx.x;
    int lane = tid & 63, wid = tid >> 6;
    int m0 = blockIdx.x * 128;
    int nb = blockIdx.y * 64;
    int g0 = tid, g1 = tid + 256;
    int r0 = g0 >> 2, r1 = g1 >> 2;
    int wtr0 = nb + ((r0>>6)<<5) + (r0&31) + ((r0>>5)&1)*1024;
    int wtr1 = nb + ((r1>>6)<<5) + (r1&31) + ((r1>>5)&1)*1024;
    const short* Ap = (const short*)Abf;
    const short* Bp = (const short*)Wt;
    const short* Ag0 = Ap + (size_t)(m0 + r0)*K + (g0&3)*8;
    const short* Ag1 = Ap + (size_t)(m0 + r1)*K + (g1&3)*8;
    const short* Bg0 = Bp + (size_t)wtr0*K + (g0&3)*8;
    const short* Bg1 = Bp + (size_t)wtr1*K + (g1&3)*8;
    char* AsB = (char*)As;
    char* BsB = (char*)Bs;
    int wr = wid >> 1, wc = wid & 1;
    int mo = wr*64, no = wc*64;
    f32x4 acc[4][4] = {};
    int arow = (lane & 15)*32 + (lane>>4)*8;
    for (int k0 = 0; k0 < K; k0 += 32){
        gload16(Ag0 + k0, AsB + wid*1024);
        gload16(Ag1 + k0, AsB + 4096 + wid*1024);
        gload16(Bg0 + k0, BsB + wid*1024);
        gload16(Bg1 + k0, BsB + 4096 + wid*1024);
        asm volatile("s_waitcnt vmcnt(0)" ::: "memory");
        __syncthreads();
        bf16x8 a[4], b[4];
        #pragma unroll
        for (int mi=0;mi<4;mi++)
            a[mi] = *(const bf16x8*)(As + (mo + mi*16)*32 + arow);
        #pragma unroll
        for (int ni=0;ni<4;ni++)
            b[ni] = *(const bf16x8*)(Bs + (no + ni*16)*32 + arow);
        #pragma unroll
        for (int mi=0;mi<4;mi++){
            #pragma unroll
            for (int ni=0;ni<4;ni++){
                acc[mi][ni] = __builtin_amdgcn_mfma_f32_16x16x32_bf16(a[mi], b[ni], acc[mi][ni], 0, 0, 0);
            }
        }
        __syncthreads();
    }
    int cbase = nb + wc*32 + (lane&15);
    #pragma unroll
    for (int ni=0;ni<2;ni++){
        int c = cbase + ni*16;
        float ba = bias2[c], bb = bias2[c+1024];
        #pragma unroll
        for (int mi=0;mi<4;mi++){
            #pragma unroll
            for (int r=0;r<4;r++){
                size_t m = m0 + mo + mi*16 + (lane>>4)*4 + r;
                float za = acc[mi][ni][r] + ba;
                float zb = acc[mi][ni+2][r] + bb;
                glu[m*H + c] = za * sigm_f(zb);
            }
        }
    }
}

// ---------------- LayerNorm over H per (b,t) row (encoder) ----------------
__global__ __launch_bounds__(256) void k_ln(const float* __restrict__ glu, const float* __restrict__ res,
        const float* __restrict__ gamma, const float* __restrict__ beta, float* __restrict__ outx){
    __shared__ float red[8];
    int row = blockIdx.x;
    int tid = threadIdx.x;
    float4 gv = *(const float4*)(glu + (size_t)row*H + tid*4);
    float4 rv = *(const float4*)(res + (size_t)row*H + tid*4);
    float x0=gv.x+rv.x, x1=gv.y+rv.y, x2=gv.z+rv.z, x3=gv.w+rv.w;
    float s = x0+x1+x2+x3;
    float q = x0*x0+x1*x1+x2*x2+x3*x3;
    #pragma unroll
    for (int m=32;m>=1;m>>=1){ s += __shfl_xor(s,m,64); q += __shfl_xor(q,m,64); }
    int wv = tid>>6;
    if ((tid&63)==0){ red[wv]=s; red[4+wv]=q; }
    __syncthreads();
    s = red[0]+red[1]+red[2]+red[3];
    q = red[4]+red[5]+red[6]+red[7];
    float m = s*(1.0f/H);
    float v = q*(1.0f/H) - m*m;
    float rstd = rsqrtf(v + 1e-5f);
    float4 gm = *(const float4*)(gamma + tid*4);
    float4 bt = *(const float4*)(beta + tid*4);
    float4 o;
    o.x = (x0-m)*rstd*gm.x + bt.x;
    o.y = (x1-m)*rstd*gm.y + bt.y;
    o.z = (x2-m)*rstd*gm.z + bt.z;
    o.w = (x3-m)*rstd*gm.w + bt.w;
    *(float4*)(outx + (size_t)row*H + tid*4) = o;
}

__global__ void k_ctx(const float* __restrict__ x, float* __restrict__ ctx){
    int i = blockIdx.x*256+threadIdx.x;
    int b = i>>10, h = i&(H-1);
    ctx[i] = x[((size_t)(b*TLEN + TLEN-1))*H + h];
}

// ======================= GROUP-LOCAL DECODE, 4 BATCHES/GROUP =======================
// (round-15 structure: 8 same-XCD groups x 32 blocks, group-local barriers)
__device__ __forceinline__ void gbar_grp(int* gfl, int jj, int g, int tid){
    __syncthreads();
    if (tid == 0)
        __hip_atomic_store(gfl + jj*FLAGSTRIDE, g, __ATOMIC_RELAXED,
                           __HIP_MEMORY_SCOPE_AGENT);
    if (tid < 32){
        int it = 0;
        while (__hip_atomic_load(gfl + tid*FLAGSTRIDE, __ATOMIC_RELAXED,
                                 __HIP_MEMORY_SCOPE_AGENT) < g){
            __builtin_amdgcn_s_sleep(1);
            if (++it > 1000000) break;
        }
    }
    __syncthreads();
}

// GEMM phase: 4 batches x (1024x2048) x GLU, coalesced W reads.
// thread = (p = tid>>3 col-pair, ks = tid&7 k-octant interleaved by 64):
// lanes 0-7 read 16B-stride CONTIGUOUS 128B of one W row -> 4x fewer lines.
// ks-reduction via 3 intra-wave shfl_xor (no LDS part array).
__device__ __forceinline__ void gemv4(int grp, int jj, int tid,
        float (*ysh)[H],
        const short* __restrict__ Wl, const float* __restrict__ b2,
        const float* __restrict__ ygel, float* __restrict__ glud){
    #pragma unroll
    for (int i=0;i<16;i++){
        int idx = i*256 + tid;
        int b4 = idx >> 10, hh = idx & 1023;
        ysh[b4][hh] = ald(&ygel[(size_t)(4*grp + b4)*H + hh]);
    }
    __syncthreads();
    int p = tid >> 3, ks = tid & 7;
    int colp = jj*32 + p;
    const short* wa = Wl + (size_t)colp*H;
    const short* wb = Wl + (size_t)(colp+1024)*H;
    float a0=0,a1=0,a2=0,a3=0, c0=0,c1=0,c2=0,c3=0;
    #pragma unroll 4
    for (int i=0;i<16;i++){
        int k = i*64 + ks*8;
        bf16x8 wva = *(const bf16x8*)(wa + k);
        bf16x8 wvb = *(const bf16x8*)(wb + k);
        float4 u00 = *(const float4*)&ysh[0][k];
        float4 u01 = *(const float4*)&ysh[0][k+4];
        float4 u10 = *(const float4*)&ysh[1][k];
        float4 u11 = *(const float4*)&ysh[1][k+4];
        float4 u20 = *(const float4*)&ysh[2][k];
        float4 u21 = *(const float4*)&ysh[2][k+4];
        float4 u30 = *(const float4*)&ysh[3][k];
        float4 u31 = *(const float4*)&ysh[3][k+4];
        float w0[8], w1[8];
        #pragma unroll
        for (int j=0;j<8;j++){ w0[j] = bf2f(wva[j]); w1[j] = bf2f(wvb[j]); }
        float ua[4][8] = {
            {u00.x,u00.y,u00.z,u00.w,u01.x,u01.y,u01.z,u01.w},
            {u10.x,u10.y,u10.z,u10.w,u11.x,u11.y,u11.z,u11.w},
            {u20.x,u20.y,u20.z,u20.w,u21.x,u21.y,u21.z,u21.w},
            {u30.x,u30.y,u30.z,u30.w,u31.x,u31.y,u31.z,u31.w}};
        #pragma unroll
        for (int j=0;j<8;j++){
            a0 = fmaf(ua[0][j], w0[j], a0);  c0 = fmaf(ua[0][j], w1[j], c0);
            a1 = fmaf(ua[1][j], w0[j], a1);  c1 = fmaf(ua[1][j], w1[j], c1);
            a2 = fmaf(ua[2][j], w0[j], a2);  c2 = fmaf(ua[2][j], w1[j], c2);
            a3 = fmaf(ua[3][j], w0[j], a3);  c3 = fmaf(ua[3][j], w1[j], c3);
        }
    }
    #pragma unroll
    for (int m=1;m<8;m<<=1){
        a0 += __shfl_xor(a0,m,64);  c0 += __shfl_xor(c0,m,64);
        a1 += __shfl_xor(a1,m,64);  c1 += __shfl_xor(c1,m,64);
        a2 += __shfl_xor(a2,m,64);  c2 += __shfl_xor(c2,m,64);
        a3 += __shfl_xor(a3,m,64);  c3 += __shfl_xor(c3,m,64);
    }
    if ((tid & 7) == 0){
        float ba = b2[colp], bb = b2[1024 + colp];
        ast(&glud[(size_t)(4*grp + 0)*H + colp], (a0 + ba) * sigm_f(c0 + bb));
        ast(&glud[(size_t)(4*grp + 1)*H + colp], (a1 + ba) * sigm_f(c1 + bb));
        ast(&glud[(size_t)(4*grp + 2)*H + colp], (a2 + ba) * sigm_f(c2 + bb));
        ast(&glud[(size_t)(4*grp + 3)*H + colp], (a3 + ba) * sigm_f(c3 + bb));
    }
}

__global__ __launch_bounds__(256, 1) void k_decode(
        const float* __restrict__ Kbuf, const float* __restrict__ Dv,
        const __hip_bfloat16* __restrict__ Wt, const float* __restrict__ bias2,
        const float* __restrict__ lng, const float* __restrict__ lnb,
        const float* __restrict__ ctx, const float* __restrict__ headw,
        const float* __restrict__ headb,
        float* __restrict__ ygel0, float* __restrict__ ygel1,
        float* __restrict__ glud0, float* __restrict__ glud1,
        float* __restrict__ out, int* __restrict__ flags){
    __shared__ float hist[16][H];
    __shared__ float ysh[4][H];
    __shared__ float red[8];
    __shared__ float bitsh[16];
    int bid = blockIdx.x;
    int grp = bid & 7, jj = bid >> 3;
    int tid = threadIdx.x;
    int lane = tid & 63, wv = tid >> 6;
    bool leader = (jj < 4);
    int b = grp*4 + jj;
    float4 dv0v, dv1v, lg0v, be0v, lg1v, be1v, cvxv, hwv;
    float hb = headb[0];
    if (leader){
        dv0v = *(const float4*)(Dv + tid*4);
        dv1v = *(const float4*)(Dv + H + tid*4);
        lg0v = *(const float4*)(lng + tid*4);
        be0v = *(const float4*)(lnb + tid*4);
        lg1v = *(const float4*)(lng + H + tid*4);
        be1v = *(const float4*)(lnb + H + tid*4);
        cvxv = *(const float4*)(ctx + (size_t)b*H + tid*4);
        hwv  = *(const float4*)(headw + tid*4);
    }
    if (tid < 16) bitsh[tid] = 0.f;
    __syncthreads();
    const short* Wt0 = (const short*)Wt;
    const short* Wt1 = (const short*)Wt + (size_t)H*H2;
    int* gfl = flags + grp*32*FLAGSTRIDE;
    int g = 1;
    for (int s=0; s<NSTEPS; s++){
        if (leader){
            if (s > 0){
                int sp = s-1;
                float x0 = ald(&glud1[(size_t)b*H + tid*4+0]);
                float x1 = ald(&glud1[(size_t)b*H + tid*4+1]);
                float x2 = ald(&glud1[(size_t)b*H + tid*4+2]);
                float x3 = ald(&glud1[(size_t)b*H + tid*4+3]);
                if (sp != 0){ x0*=2.f; x1*=2.f; x2*=2.f; x3*=2.f; }
                float su = x0+x1+x2+x3, qu = x0*x0+x1*x1+x2*x2+x3*x3;
                #pragma unroll
                for (int m=32;m>=1;m>>=1){ su += __shfl_xor(su,m,64); qu += __shfl_xor(qu,m,64); }
                if (lane==0){ red[wv]=su; red[4+wv]=qu; }
                __syncthreads();
                float S = red[0]+red[1]+red[2]+red[3];
                float Q = red[4]+red[5]+red[6]+red[7];
                float mean = S*(1.f/H), var = Q*(1.f/H)-mean*mean;
                float rstd = rsqrtf(var + 1e-5f);
                float d0 = (x0-mean)*rstd*lg1v.x + be1v.x + cvxv.x;
                float d1 = (x1-mean)*rstd*lg1v.y + be1v.y + cvxv.y;
                float d2 = (x2-mean)*rstd*lg1v.z + be1v.z + cvxv.z;
                float d3 = (x3-mean)*rstd*lg1v.w + be1v.w + cvxv.w;
                float hp = d0*hwv.x + d1*hwv.y + d2*hwv.z + d3*hwv.w;
                #pragma unroll
                for (int m=32;m>=1;m>>=1) hp += __shfl_xor(hp,m,64);
                __syncthreads();
                if (lane==0) red[wv] = hp;
                __syncthreads();
                float hs = red[0]+red[1]+red[2]+red[3] + hb;
                float bit = sigm_f(hs);
                if (tid==0){ out[b*NSTEPS + sp] = bit; bitsh[sp] = bit; }
                __syncthreads();
            }
            float bu = (s==0) ? 0.f : bitsh[s-1];
            float dvs[4] = {dv0v.x, dv0v.y, dv0v.z, dv0v.w};
            #pragma unroll
            for (int i=0;i<4;i++){
                int h = tid*4+i;
                const float* Kr = Kbuf + (size_t)h*TLEN;
                float y0 = dvs[i]*bu;
                #pragma unroll
                for (int d=0; d<16; d++){
                    int idx = s-1-d;
                    float uv = (idx >= 0) ? bitsh[idx] : 0.f;
                    y0 = fmaf(Kr[d], uv, y0);
                }
                ast(&ygel0[(size_t)b*H + h], gelu_f(y0));
            }
        }
        gbar_grp(gfl, jj, g++, tid);
        gemv4(grp, jj, tid, ysh, Wt0, bias2, ygel0, glud0);
        gbar_grp(gfl, jj, g++, tid);
        if (leader){
            float x0 = ald(&glud0[(size_t)b*H + tid*4+0]);
            float x1 = ald(&glud0[(size_t)b*H + tid*4+1]);
            float x2 = ald(&glud0[(size_t)b*H + tid*4+2]);
            float x3 = ald(&glud0[(size_t)b*H + tid*4+3]);
            if (s != 0){ x0*=2.f; x1*=2.f; x2*=2.f; x3*=2.f; }
            float su = x0+x1+x2+x3, qu = x0*x0+x1*x1+x2*x2+x3*x3;
            #pragma unroll
            for (int m=32;m>=1;m>>=1){ su += __shfl_xor(su,m,64); qu += __shfl_xor(qu,m,64); }
            if (lane==0){ red[wv]=su; red[4+wv]=qu; }
            __syncthreads();
            float S = red[0]+red[1]+red[2]+red[3];
            float Q = red[4]+red[5]+red[6]+red[7];
            float mean = S*(1.f/H), var = Q*(1.f/H)-mean*mean;
            float rstd = rsqrtf(var + 1e-5f);
            float dd[4];
            dd[0] = (x0-mean)*rstd*lg0v.x + be0v.x;
            dd[1] = (x1-mean)*rstd*lg0v.y + be0v.y;
            dd[2] = (x2-mean)*rstd*lg0v.z + be0v.z;
            dd[3] = (x3-mean)*rstd*lg0v.w + be0v.w;
            float dvs[4] = {dv1v.x, dv1v.y, dv1v.z, dv1v.w};
            #pragma unroll
            for (int i=0;i<4;i++){
                int h = tid*4+i;
                hist[s & 15][h] = dd[i];
                const float* Kr = Kbuf + (size_t)(H+h)*TLEN;
                float y1 = dvs[i]*dd[i];
                #pragma unroll
                for (int d=0; d<16; d++){
                    int sd = s-d;
                    float uv = (sd >= 0) ? hist[sd & 15][h] : 0.f;
                    y1 = fmaf(Kr[d], uv, y1);
                }
                ast(&ygel1[(size_t)b*H + h], gelu_f(y1));
            }
        }
        gbar_grp(gfl, jj, g++, tid);
        gemv4(grp, jj, tid, ysh, Wt1, bias2 + H2, ygel1, glud1);
        gbar_grp(gfl, jj, g++, tid);
    }
    if (leader){
        float x0 = 2.f*ald(&glud1[(size_t)b*H + tid*4+0]);
        float x1 = 2.f*ald(&glud1[(size_t)b*H + tid*4+1]);
        float x2 = 2.f*ald(&glud1[(size_t)b*H + tid*4+2]);
        float x3 = 2.f*ald(&glud1[(size_t)b*H + tid*4+3]);
        float su = x0+x1+x2+x3, qu = x0*x0+x1*x1+x2*x2+x3*x3;
        #pragma unroll
        for (int m=32;m>=1;m>>=1){ su += __shfl_xor(su,m,64); qu += __shfl_xor(qu,m,64); }
        if (lane==0){ red[wv]=su; red[4+wv]=qu; }
        __syncthreads();
        float S = red[0]+red[1]+red[2]+red[3];
        float Q = red[4]+red[5]+red[6]+red[7];
        float mean = S*(1.f/H), var = Q*(1.f/H)-mean*mean;
        float rstd = rsqrtf(var + 1e-5f);
        float d0 = (x0-mean)*rstd*lg1v.x + be1v.x + cvxv.x;
        float d1 = (x1-mean)*rstd*lg1v.y + be1v.y + cvxv.y;
        float d2 = (x2-mean)*rstd*lg1v.z + be1v.z + cvxv.z;
        float d3 = (x3-mean)*rstd*lg1v.w + be1v.w + cvxv.w;
        float hp = d0*hwv.x + d1*hwv.y + d2*hwv.z + d3*hwv.w;
        #pragma unroll
        for (int m=32;m>=1;m>>=1) hp += __shfl_xor(hp,m,64);
        __syncthreads();
        if (lane==0) red[wv] = hp;
        __syncthreads();
        float hs = red[0]+red[1]+red[2]+red[3] + hb;
        if (tid==0) out[b*NSTEPS + 15] = sigm_f(hs);
    }
}

extern "C" void kernel_launch(void* const* d_in, const int* in_sizes, int n_in,
                              void* d_out, int out_size, void* d_ws, size_t ws_size,
                              hipStream_t stream) {
    const float* in_seq = (const float*)d_in[0];
    const float* inw  = (const float*)d_in[2];
    const float* inb  = (const float*)d_in[3];
    const float* log_dt = (const float*)d_in[4];
    const float* Are = (const float*)d_in[5];
    const float* Aim = (const float*)d_in[6];
    const float* Bre = (const float*)d_in[7];
    const float* Bim = (const float*)d_in[8];
    const float* Cre = (const float*)d_in[9];
    const float* Cim = (const float*)d_in[10];
    const float* Dv  = (const float*)d_in[11];
    const float* outw = (const float*)d_in[12];
    const float* outb = (const float*)d_in[13];
    const float* lng = (const float*)d_in[14];
    const float* lnb = (const float*)d_in[15];
    const float* headw = (const float*)d_in[16];
    const float* headb = (const float*)d_in[17];
    float* out = (float*)d_out;

    float* ws = (float*)d_ws;
    size_t off = 0;
    auto alloc = [&](size_t n){ float* p = ws + off; off += n; return p; };
    float* dAr = alloc((size_t)LAYN*H*NST);
    float* dAi = alloc((size_t)LAYN*H*NST);
    float* dBr = alloc((size_t)LAYN*H*NST);
    float* dBi = alloc((size_t)LAYN*H*NST);
    float* Kbuf = alloc((size_t)LAYN*H*TLEN);
    float* bufA = alloc((size_t)BSZ*TLEN*H);                              // 67MB
    float* bufB = alloc((size_t)BSZ*TLEN*H);                              // 67MB
    __hip_bfloat16* gbf = (__hip_bfloat16*)alloc((size_t)BSZ*TLEN*H/2);   // 33.5MB
    __hip_bfloat16* Abf = (__hip_bfloat16*)alloc((size_t)BSZ*TLEN*H/2);   // 33.5MB
    __hip_bfloat16* Wt  = (__hip_bfloat16*)alloc((size_t)LAYN*H*H2/2);    // 8.4MB
    float* ctx = alloc((size_t)BSZ*H);
    float* ygel0 = alloc((size_t)BSZ*H);
    float* ygel1 = alloc((size_t)BSZ*H);
    float* glud0 = alloc((size_t)BSZ*H);
    float* glud1 = alloc((size_t)BSZ*H);
    int*   flags = (int*)alloc((size_t)NGRP*32*FLAGSTRIDE);
    // total ~217 MB (round-3's proven 241.7 MB OK; round-4's 283.6 MB crashed)

    k_precompute<<<(LAYN*H*NST+255)/256, 256, 0, stream>>>(log_dt,Are,Aim,Bre,Bim,dAr,dAi,dBr,dBi);
    k_genK<<<LAYN*H, 64, 0, stream>>>(dAr,dAi,dBr,dBi,Cre,Cim,Kbuf);
    k_wtr<<<dim3(H2/32, H/32, LAYN), 256, 0, stream>>>(outw, Wt);
    k_inproj_x <<<(BSZ*TLEN*H)/256, 256, 0, stream>>>(in_seq, inw, inb, bufA);
    k_inproj_xT<<<(BSZ*TLEN*H)/256, 256, 0, stream>>>(in_seq, inw, inb, bufB);

    // ---- layer 0: res = bufA (b,t,h); xT = bufB (b,h,t)
    k_conv_mfma<<<dim3(H), 256, 0, stream>>>(bufB, Kbuf, Dv, gbf, 0);
    k_trcast_bf<<<dim3(TLEN/32, H/32, BSZ), 256, 0, stream>>>(gbf, Abf);
    k_gemm_glu_mfma<<<dim3(BSZ*TLEN/128, H/64), 256, 0, stream>>>(Abf, Wt, outb, bufB);
    k_ln<<<BSZ*TLEN, 256, 0, stream>>>(bufB, bufA, lng, lnb, bufA);
    k_transpose<<<dim3(16,32,32), 256, 0, stream>>>(bufA, bufB);

    // ---- layer 1
    k_conv_mfma<<<dim3(H), 256, 0, stream>>>(bufB, Kbuf, Dv, gbf, 1);
    k_trcast_bf<<<dim3(TLEN/32, H/32, BSZ), 256, 0, stream>>>(gbf, Abf);
    k_gemm_glu_mfma<<<dim3(BSZ*TLEN/128, H/64), 256, 0, stream>>>(Abf, Wt + (size_t)H*H2, outb + H2, bufB);
    k_ln<<<BSZ*TLEN, 256, 0, stream>>>(bufB, bufA, lng+H, lnb+H, bufA);

    k_ctx<<<(BSZ*H)/256, 256, 0, stream>>>(bufA, ctx);

    // ---- decode: 8 same-XCD groups x 4 batches, group-local barriers
    hipMemsetAsync(flags, 0, sizeof(int)*(size_t)NGRP*32*FLAGSTRIDE, stream);
    k_decode<<<NGRP*32, 256, 0, stream>>>(Kbuf, Dv, Wt, outb, lng, lnb,
                                          ctx, headw, headb,
                                          ygel0, ygel1, glud0, glud1, out, flags);
}